// Round 8
// baseline (428.492 us; speedup 1.0000x reference)
//
#include <hip/hip_runtime.h>
#include <hip/hip_bf16.h>
#include <math.h>

#define N_TOK 8192
#define DDIM  1024
#define HDIM  4096
#define NBLK  512

typedef __bf16 bf16x8 __attribute__((ext_vector_type(8)));
typedef __bf16 bf16x4 __attribute__((ext_vector_type(4)));
typedef float  floatx4 __attribute__((ext_vector_type(4)));

__device__ __forceinline__ float wave_reduce_sum(float v) {
#pragma unroll
    for (int off = 32; off > 0; off >>= 1) v += __shfl_down(v, off, 64);
    return v;
}

__device__ __forceinline__ void gload_lds16(const void* g, void* l) {
    __builtin_amdgcn_global_load_lds((const __attribute__((address_space(1))) void*)g,
                                     (__attribute__((address_space(3))) void*)l,
                                     16, 0, 0);
}

// Branchless gelu via A&S 7.1.26 erf (max err 1.5e-7), ~13 VALU ops.
__device__ __forceinline__ float fast_gelu(float x) {
    float ax = fabsf(x);
    float z  = ax * 0.70710678118654752f;
    float t  = __builtin_amdgcn_rcpf(fmaf(0.3275911f, z, 1.0f));
    float p  = fmaf(fmaf(fmaf(fmaf(1.061405429f, t, -1.453152027f),
                              t, 1.421413741f),
                         t, -0.284496736f),
                    t, 0.254829592f);
    p *= t;
    float e = __expf(-z * z);
    float E = fmaf(-p, e, 1.0f);
    return 0.5f * fmaf(ax, E, x);
}

__device__ __forceinline__ float fast_softplus(float r) {
    return __logf(fmaf(1.0f, __expf(r), 1.0f));
}

// ---------------------------------------------------------------------------
// Fused prep kernel: unit rows / LN+x-cast / W casts
// ---------------------------------------------------------------------------
__device__ __forceinline__ void cast1024(const float* __restrict__ s,
                                         __bf16* __restrict__ d,
                                         size_t off, int t) {
    float4 v = ((const float4*)(s + off))[t];
    bf16x4 o;
    o.x = (__bf16)v.x; o.y = (__bf16)v.y;
    o.z = (__bf16)v.z; o.w = (__bf16)v.w;
    ((bf16x4*)(d + off))[t] = o;
}

__global__ __launch_bounds__(256) void prep_kernel(
        const float* __restrict__ x,
        const float* __restrict__ ln_g, const float* __restrict__ ln_b,
        const float* __restrict__ W1,   const float* __restrict__ W2,
        const float* __restrict__ router_W,
        const float* __restrict__ rawU, const float* __restrict__ rawV,
        __bf16* __restrict__ xb,  __bf16* __restrict__ lnb,
        __bf16* __restrict__ w1b, __bf16* __restrict__ w2b,
        __bf16* __restrict__ rwb,
        float* __restrict__ unitU, float* __restrict__ unitV) {
    int b = blockIdx.x;
    int t = threadIdx.x;

    if (b < 1024) {
        const float* src = (b < NBLK) ? rawU + (size_t)b * DDIM
                                      : rawV + (size_t)(b - NBLK) * DDIM;
        float* dst = (b < NBLK) ? unitU + (size_t)b * DDIM
                                : unitV + (size_t)(b - NBLK) * DDIM;
        float vals[4];
        float ss = 0.f;
#pragma unroll
        for (int i = 0; i < 4; i++) { vals[i] = src[t + i * 256]; ss += vals[i] * vals[i]; }
        __shared__ float red[4];
        ss = wave_reduce_sum(ss);
        if ((t & 63) == 0) red[t >> 6] = ss;
        __syncthreads();
        float tot = red[0] + red[1] + red[2] + red[3];
        float inv = 1.f / fmaxf(sqrtf(tot), 1e-6f);
#pragma unroll
        for (int i = 0; i < 4; i++) dst[t + i * 256] = vals[i] * inv;
    } else if (b < 9216) {
        int n = b - 1024;
        const float* row = x + (size_t)n * DDIM;
        float v[4];
        float s1 = 0.f, s2 = 0.f;
#pragma unroll
        for (int i = 0; i < 4; i++) {
            v[i] = row[t + i * 256];
            s1 += v[i];
            s2 += v[i] * v[i];
        }
        __shared__ float r1[4], r2[4];
        s1 = wave_reduce_sum(s1);
        s2 = wave_reduce_sum(s2);
        if ((t & 63) == 0) { r1[t >> 6] = s1; r2[t >> 6] = s2; }
        __syncthreads();
        float mu  = (r1[0] + r1[1] + r1[2] + r1[3]) * (1.f / DDIM);
        float var = (r2[0] + r2[1] + r2[2] + r2[3]) * (1.f / DDIM) - mu * mu;
        float rstd = rsqrtf(var + 1e-5f);
        __bf16* orow = lnb + (size_t)n * DDIM;
        __bf16* xrow = xb  + (size_t)n * DDIM;
#pragma unroll
        for (int i = 0; i < 4; i++) {
            int d = t + i * 256;
            orow[d] = (__bf16)((v[i] - mu) * rstd * ln_g[d] + ln_b[d]);
            xrow[d] = (__bf16)v[i];
        }
    } else if (b < 13312) {
        cast1024(W1, w1b, (size_t)(b - 9216) * 1024, t);
    } else if (b < 17408) {
        cast1024(W2, w2b, (size_t)(b - 13312) * 1024, t);
    } else {
        cast1024(router_W, rwb, (size_t)(b - 17408) * 1024, t);
    }
}

// ---------------------------------------------------------------------------
// bf16 MFMA NT GEMM, 128x128 tile, BK=32, double-buffered LDS, one barrier
// per K-iter. 256 threads = 4 waves (2x2), wave tile 64x64.
// SPLITK is COMPILE-TIME (runtime gridDim.z division broke const-folding and
// cost ~6% on all instantiations in R7).
// MODE 0: unsafeAtomicAdd raw acc -> fp32 (router split-K; bias/softplus
//         applied by the consumer — softplus∘clip is monotone so top-k on
//         raw scores is identical)
// MODE 1: D = fast_gelu(acc) -> bf16                  (gemm1)
// MODE 2: C += acc (fp32 rmw)                         (gemm2)
// ---------------------------------------------------------------------------
template <int MODE, int SPLITK>
__global__ __launch_bounds__(256) void mfma_gemm(const __bf16* __restrict__ A,
                                                 const __bf16* __restrict__ B,
                                                 void* __restrict__ Cv,
                                                 int M, int Nn, int Kk) {
    __shared__ __align__(16) __bf16 As[2][128 * 32];   // 2 x 8 KB
    __shared__ __align__(16) __bf16 Bs[2][128 * 32];   // 2 x 8 KB

    const int t    = threadIdx.x;
    const int lane = t & 63;
    const int wave = t >> 6;
    const int wm   = wave >> 1, wn = wave & 1;
    const int lr   = lane & 15, quad = lane >> 4;
    const int m0   = blockIdx.x * 128;
    const int n0   = blockIdx.y * 128;

    const int kLen  = Kk / SPLITK;                       // compile-time divisor
    const int kBase = (SPLITK == 1) ? 0 : blockIdx.z * kLen;

    const int ca0 = t & 3;
    const __bf16* Ag[2];
    const __bf16* Bg[2];
    int ldsOff[2];
#pragma unroll
    for (int q = 0; q < 2; q++) {
        int idx = q * 256 + t;
        Ag[q]     = A + (size_t)(m0 + (idx >> 2)) * Kk + kBase + ca0 * 8;
        Bg[q]     = B + (size_t)(n0 + (idx >> 2)) * Kk + kBase + ca0 * 8;
        ldsOff[q] = idx * 8;
    }

    int raOff[4], rbOff[4];
#pragma unroll
    for (int i = 0; i < 4; i++) {
        raOff[i] = (wm * 64 + i * 16 + lr) * 32 + quad * 8;
        rbOff[i] = (wn * 64 + i * 16 + lr) * 32 + quad * 8;
    }

    floatx4 acc[4][4];
#pragma unroll
    for (int i = 0; i < 4; i++)
#pragma unroll
        for (int j = 0; j < 4; j++) acc[i][j] = (floatx4)0.f;

#pragma unroll
    for (int q = 0; q < 2; q++) {
        gload_lds16(Ag[q], &As[0][ldsOff[q]]);
        gload_lds16(Bg[q], &Bs[0][ldsOff[q]]);
    }

    const int niter = kLen >> 5;
    for (int it = 0; it < niter; ++it) {
        const int cur = it & 1;
        __syncthreads();
        if (it + 1 < niter) {
            const int nk = (it + 1) << 5;
            const int nb = cur ^ 1;
#pragma unroll
            for (int q = 0; q < 2; q++) {
                gload_lds16(Ag[q] + nk, &As[nb][ldsOff[q]]);
                gload_lds16(Bg[q] + nk, &Bs[nb][ldsOff[q]]);
            }
        }
        bf16x8 af[4], bfr[4];
#pragma unroll
        for (int i = 0; i < 4; i++) af[i]  = *(const bf16x8*)&As[cur][raOff[i]];
#pragma unroll
        for (int j = 0; j < 4; j++) bfr[j] = *(const bf16x8*)&Bs[cur][rbOff[j]];
#pragma unroll
        for (int i = 0; i < 4; i++)
#pragma unroll
            for (int j = 0; j < 4; j++)
                acc[i][j] = __builtin_amdgcn_mfma_f32_16x16x32_bf16(af[i], bfr[j],
                                                                    acc[i][j], 0, 0, 0);
    }

    const int mBase = m0 + wm * 64 + quad * 4;
    const int nBase = n0 + wn * 64 + lr;
#pragma unroll
    for (int i = 0; i < 4; i++) {
#pragma unroll
        for (int j = 0; j < 4; j++) {
            int n = nBase + j * 16;
#pragma unroll
            for (int r = 0; r < 4; r++) {
                int m = mBase + i * 16 + r;
                float v = acc[i][j][r];
                if (MODE == 0) {
                    unsafeAtomicAdd(&((float*)Cv)[(size_t)m * Nn + n], v);
                } else if (MODE == 1) {
                    ((__bf16*)Cv)[(size_t)m * Nn + n] = (__bf16)fast_gelu(v);
                } else {
                    ((float*)Cv)[(size_t)m * Nn + n] += v;
                }
            }
        }
    }
}

// ---------------------------------------------------------------------------
// Fused top-8 + dynamic path: one block (256 thr) per token.
// Reads RAW router scores (split-K partial-summed), adds bias, selects top-8
// on raw r (== top-8 on softplus(clip(r)) by monotonicity; |r|<<TAU so no
// clip ties), then applies clip+softplus to the 8 winners only.
// ---------------------------------------------------------------------------
__global__ __launch_bounds__(256) void topk_dyn_kernel(
        const float* __restrict__ rraw,
        const float* __restrict__ router_b,
        const float* __restrict__ x,
        const float* __restrict__ unitU,
        const float* __restrict__ unitV,
        const float* __restrict__ gamma,
        float* __restrict__ out) {
    int n = blockIdx.x;
    int t = threadIdx.x;
    int lane = t & 63, wid = t >> 6;

    __shared__ int   sidx[8];
    __shared__ float shz[8];
    __shared__ float red[8][4];
    __shared__ float hz[8];

    if (wid == 0) {
        const float* row = rraw + (size_t)n * NBLK;
        float v[8];
#pragma unroll
        for (int i = 0; i < 8; i++) v[i] = row[lane + i * 64] + router_b[lane + i * 64];
        float topv[8];
        int   topi[8];
        for (int s = 0; s < 8; s++) {
            float bv = v[0]; int bi = 0;
#pragma unroll
            for (int i = 1; i < 8; i++)
                if (v[i] > bv) { bv = v[i]; bi = i; }
            int gidx = lane + bi * 64;
#pragma unroll
            for (int off = 1; off < 64; off <<= 1) {
                float ov = __shfl_xor(bv, off, 64);
                int   oi = __shfl_xor(gidx, off, 64);
                if (ov > bv || (ov == bv && oi < gidx)) { bv = ov; gidx = oi; }
            }
            topv[s] = bv; topi[s] = gidx;
            if ((gidx & 63) == lane) v[gidx >> 6] = -1e30f;
        }
        float phi[8];
        float S = 0.f;
#pragma unroll
        for (int s = 0; s < 8; s++) {
            float rr = fminf(fmaxf(topv[s], -10.f), 10.f);
            phi[s] = fast_softplus(rr);
            S += phi[s];
        }
        float zscale = tanhf(S) / (S + 1e-6f);
        if (lane < 8) {
            sidx[lane] = topi[lane];
            shz[lane]  = phi[lane] * zscale;
        }
    }
    __syncthreads();

    const float* xr = x + (size_t)n * DDIM;
    float xv[4];
#pragma unroll
    for (int i = 0; i < 4; i++) xv[i] = xr[t + i * 256];

    float acc[8];
#pragma unroll
    for (int k = 0; k < 8; k++) {
        const float* ur = unitU + (size_t)sidx[k] * DDIM;
        float a = 0.f;
#pragma unroll
        for (int i = 0; i < 4; i++) a = fmaf(xv[i], ur[t + i * 256], a);
        acc[k] = a;
    }
#pragma unroll
    for (int k = 0; k < 8; k++) {
        float a = wave_reduce_sum(acc[k]);
        if (lane == 0) red[k][wid] = a;
    }
    __syncthreads();
    if (t < 8) {
        float h = red[t][0] + red[t][1] + red[t][2] + red[t][3];
        hz[t] = h * shz[t];
    }
    __syncthreads();

    float* orow = out + (size_t)n * DDIM;
#pragma unroll
    for (int i = 0; i < 4; i++) {
        int d = t + i * 256;
        float s = 0.f;
#pragma unroll
        for (int k = 0; k < 8; k++)
            s = fmaf(hz[k], unitV[(size_t)sidx[k] * DDIM + d], s);
        orow[d] = s * gamma[d];
    }
}

// ---------------------------------------------------------------------------
extern "C" void kernel_launch(void* const* d_in, const int* in_sizes, int n_in,
                              void* d_out, int out_size, void* d_ws, size_t ws_size,
                              hipStream_t stream) {
    const float* x        = (const float*)d_in[0];
    const float* W1       = (const float*)d_in[1];
    const float* W2       = (const float*)d_in[2];
    const float* ln_g     = (const float*)d_in[3];
    const float* ln_b     = (const float*)d_in[4];
    const float* router_W = (const float*)d_in[5];
    const float* router_b = (const float*)d_in[6];
    const float* raw_U    = (const float*)d_in[7];
    const float* raw_V    = (const float*)d_in[8];
    const float* gamma    = (const float*)d_in[9];
    float* out = (float*)d_out;

    char* ws = (char*)d_ws;
    __bf16* lnb   = (__bf16*)(ws);                 // 16,777,216 B
    float*  alpha = (float*)(ws + 16777216u);      // 16,777,216 B (raw router scores)
    __bf16* g1    = (__bf16*)(ws);                 // 67,108,864 B (after topk_dyn)
    __bf16* xb    = (__bf16*)(ws + 67108864u);     // 16,777,216 B
    __bf16* w1b   = (__bf16*)(ws + 83886080u);     //  8,388,608 B
    __bf16* w2b   = (__bf16*)(ws + 92274688u);     //  8,388,608 B
    __bf16* rwb   = (__bf16*)(ws + 100663296u);    //  1,048,576 B
    float*  unitU = (float*)(ws + 101711872u);     //  2,097,152 B
    float*  unitV = (float*)(ws + 103809024u);     //  2,097,152 B

    prep_kernel<<<17920, 256, 0, stream>>>(x, ln_g, ln_b, W1, W2, router_W,
                                           raw_U, raw_V, xb, lnb, w1b, w2b, rwb,
                                           unitU, unitV);

    // router raw scores, split-K=4 (compile-time), fp32 atomics into zeroed buf
    hipMemsetAsync((void*)alpha, 0, (size_t)N_TOK * NBLK * 4, stream);
    dim3 gR(N_TOK / 128, NBLK / 128, 4);
    mfma_gemm<0, 4><<<gR, 256, 0, stream>>>(lnb, rwb, (void*)alpha, N_TOK, NBLK, DDIM);

    // fused top-8 (on raw scores + bias) + dynamic path (overwrites out)
    topk_dyn_kernel<<<N_TOK, 256, 0, stream>>>(alpha, router_b, x, unitU, unitV,
                                               gamma, out);

    // gemm1: g1 = gelu(x @ W1^T) -> bf16
    dim3 g1d(N_TOK / 128, HDIM / 128);
    mfma_gemm<1, 1><<<g1d, 256, 0, stream>>>(xb, w1b, (void*)g1, N_TOK, HDIM, DDIM);

    // gemm2: out += g1 @ W2^T
    dim3 g2d(N_TOK / 128, DDIM / 128);
    mfma_gemm<2, 1><<<g2d, 256, 0, stream>>>(g1, w2b, (void*)out, N_TOK, DDIM, HDIM);
}

// Round 9
// 380.161 us; speedup vs baseline: 1.1271x; 1.1271x over previous
//
#include <hip/hip_runtime.h>
#include <hip/hip_bf16.h>
#include <math.h>

#define N_TOK 8192
#define DDIM  1024
#define HDIM  4096
#define NBLK  512

typedef __bf16 bf16x8 __attribute__((ext_vector_type(8)));
typedef __bf16 bf16x4 __attribute__((ext_vector_type(4)));
typedef float  floatx4 __attribute__((ext_vector_type(4)));

__device__ __forceinline__ float wave_reduce_sum(float v) {
#pragma unroll
    for (int off = 32; off > 0; off >>= 1) v += __shfl_down(v, off, 64);
    return v;
}

__device__ __forceinline__ void gload_lds16(const void* g, void* l) {
    __builtin_amdgcn_global_load_lds((const __attribute__((address_space(1))) void*)g,
                                     (__attribute__((address_space(3))) void*)l,
                                     16, 0, 0);
}

// Branchless gelu via A&S 7.1.26 erf (max err 1.5e-7), ~13 VALU ops.
__device__ __forceinline__ float fast_gelu(float x) {
    float ax = fabsf(x);
    float z  = ax * 0.70710678118654752f;
    float t  = __builtin_amdgcn_rcpf(fmaf(0.3275911f, z, 1.0f));
    float p  = fmaf(fmaf(fmaf(fmaf(1.061405429f, t, -1.453152027f),
                              t, 1.421413741f),
                         t, -0.284496736f),
                    t, 0.254829592f);
    p *= t;
    float e = __expf(-z * z);
    float E = fmaf(-p, e, 1.0f);
    return 0.5f * fmaf(ax, E, x);
}

__device__ __forceinline__ float fast_softplus(float r) {
    return __logf(fmaf(1.0f, __expf(r), 1.0f));
}

// ---------------------------------------------------------------------------
// Fused prep kernel: unit rows / LN+x-cast / W casts
// ---------------------------------------------------------------------------
__device__ __forceinline__ void cast1024(const float* __restrict__ s,
                                         __bf16* __restrict__ d,
                                         size_t off, int t) {
    float4 v = ((const float4*)(s + off))[t];
    bf16x4 o;
    o.x = (__bf16)v.x; o.y = (__bf16)v.y;
    o.z = (__bf16)v.z; o.w = (__bf16)v.w;
    ((bf16x4*)(d + off))[t] = o;
}

__global__ __launch_bounds__(256) void prep_kernel(
        const float* __restrict__ x,
        const float* __restrict__ ln_g, const float* __restrict__ ln_b,
        const float* __restrict__ W1,   const float* __restrict__ W2,
        const float* __restrict__ router_W,
        const float* __restrict__ rawU, const float* __restrict__ rawV,
        __bf16* __restrict__ xb,  __bf16* __restrict__ lnb,
        __bf16* __restrict__ w1b, __bf16* __restrict__ w2b,
        __bf16* __restrict__ rwb,
        float* __restrict__ unitU, float* __restrict__ unitV) {
    int b = blockIdx.x;
    int t = threadIdx.x;

    if (b < 1024) {
        const float* src = (b < NBLK) ? rawU + (size_t)b * DDIM
                                      : rawV + (size_t)(b - NBLK) * DDIM;
        float* dst = (b < NBLK) ? unitU + (size_t)b * DDIM
                                : unitV + (size_t)(b - NBLK) * DDIM;
        float vals[4];
        float ss = 0.f;
#pragma unroll
        for (int i = 0; i < 4; i++) { vals[i] = src[t + i * 256]; ss += vals[i] * vals[i]; }
        __shared__ float red[4];
        ss = wave_reduce_sum(ss);
        if ((t & 63) == 0) red[t >> 6] = ss;
        __syncthreads();
        float tot = red[0] + red[1] + red[2] + red[3];
        float inv = 1.f / fmaxf(sqrtf(tot), 1e-6f);
#pragma unroll
        for (int i = 0; i < 4; i++) dst[t + i * 256] = vals[i] * inv;
    } else if (b < 9216) {
        int n = b - 1024;
        const float* row = x + (size_t)n * DDIM;
        float v[4];
        float s1 = 0.f, s2 = 0.f;
#pragma unroll
        for (int i = 0; i < 4; i++) {
            v[i] = row[t + i * 256];
            s1 += v[i];
            s2 += v[i] * v[i];
        }
        __shared__ float r1[4], r2[4];
        s1 = wave_reduce_sum(s1);
        s2 = wave_reduce_sum(s2);
        if ((t & 63) == 0) { r1[t >> 6] = s1; r2[t >> 6] = s2; }
        __syncthreads();
        float mu  = (r1[0] + r1[1] + r1[2] + r1[3]) * (1.f / DDIM);
        float var = (r2[0] + r2[1] + r2[2] + r2[3]) * (1.f / DDIM) - mu * mu;
        float rstd = rsqrtf(var + 1e-5f);
        __bf16* orow = lnb + (size_t)n * DDIM;
        __bf16* xrow = xb  + (size_t)n * DDIM;
#pragma unroll
        for (int i = 0; i < 4; i++) {
            int d = t + i * 256;
            orow[d] = (__bf16)((v[i] - mu) * rstd * ln_g[d] + ln_b[d]);
            xrow[d] = (__bf16)v[i];
        }
    } else if (b < 13312) {
        cast1024(W1, w1b, (size_t)(b - 9216) * 1024, t);
    } else if (b < 17408) {
        cast1024(W2, w2b, (size_t)(b - 13312) * 1024, t);
    } else {
        cast1024(router_W, rwb, (size_t)(b - 17408) * 1024, t);
    }
}

// ---------------------------------------------------------------------------
// bf16 MFMA NT GEMM, 128xBN tile, BK=32, double-buffered LDS, one barrier
// per K-iter. 256 threads = 4 waves (2x2), wave tile 64x(BN/2).
// BN=128 for the compute-rich gemm1; BN=64 for grid-starved gemm2/router
// (doubles resident blocks -> latency hiding; we are latency-bound).
// MODE 0: D = fast_softplus(clip(acc+bias)) -> fp32   (router)
// MODE 1: D = fast_gelu(acc) -> bf16                  (gemm1)
// MODE 2: C += acc (fp32 rmw)                         (gemm2)
// ---------------------------------------------------------------------------
template <int MODE, int BN>
__global__ __launch_bounds__(256) void mfma_gemm(const __bf16* __restrict__ A,
                                                 const __bf16* __restrict__ B,
                                                 const float* __restrict__ bias,
                                                 void* __restrict__ Cv,
                                                 int M, int Nn, int Kk) {
    constexpr int NJ  = BN / 32;    // j-tiles per wave
    constexpr int NQB = BN / 64;    // B staging chunks per thread
    __shared__ __align__(16) __bf16 As[2][128 * 32];
    __shared__ __align__(16) __bf16 Bs[2][BN * 32];

    const int t    = threadIdx.x;
    const int lane = t & 63;
    const int wave = t >> 6;
    const int wm   = wave >> 1, wn = wave & 1;
    const int lr   = lane & 15, quad = lane >> 4;
    const int m0   = blockIdx.x * 128;
    const int n0   = blockIdx.y * BN;

    const int ca0 = t & 3;
    const __bf16* Ag[2];
    const __bf16* Bg[NQB];
    int ldsOffA[2], ldsOffB[NQB];
#pragma unroll
    for (int q = 0; q < 2; q++) {
        int idx = q * 256 + t;
        Ag[q]      = A + (size_t)(m0 + (idx >> 2)) * Kk + ca0 * 8;
        ldsOffA[q] = idx * 8;
    }
#pragma unroll
    for (int q = 0; q < NQB; q++) {
        int idx = q * 256 + t;
        Bg[q]      = B + (size_t)(n0 + (idx >> 2)) * Kk + ca0 * 8;
        ldsOffB[q] = idx * 8;
    }

    int raOff[4], rbOff[NJ];
#pragma unroll
    for (int i = 0; i < 4; i++)
        raOff[i] = (wm * 64 + i * 16 + lr) * 32 + quad * 8;
#pragma unroll
    for (int j = 0; j < NJ; j++)
        rbOff[j] = (wn * (BN / 2) + j * 16 + lr) * 32 + quad * 8;

    floatx4 acc[4][NJ];
#pragma unroll
    for (int i = 0; i < 4; i++)
#pragma unroll
        for (int j = 0; j < NJ; j++) acc[i][j] = (floatx4)0.f;

#pragma unroll
    for (int q = 0; q < 2; q++)   gload_lds16(Ag[q], &As[0][ldsOffA[q]]);
#pragma unroll
    for (int q = 0; q < NQB; q++) gload_lds16(Bg[q], &Bs[0][ldsOffB[q]]);

    const int niter = Kk >> 5;
    for (int it = 0; it < niter; ++it) {
        const int cur = it & 1;
        __syncthreads();
        if (it + 1 < niter) {
            const int nk = (it + 1) << 5;
            const int nb = cur ^ 1;
#pragma unroll
            for (int q = 0; q < 2; q++)   gload_lds16(Ag[q] + nk, &As[nb][ldsOffA[q]]);
#pragma unroll
            for (int q = 0; q < NQB; q++) gload_lds16(Bg[q] + nk, &Bs[nb][ldsOffB[q]]);
        }
        bf16x8 af[4], bfr[NJ];
#pragma unroll
        for (int i = 0; i < 4; i++)  af[i]  = *(const bf16x8*)&As[cur][raOff[i]];
#pragma unroll
        for (int j = 0; j < NJ; j++) bfr[j] = *(const bf16x8*)&Bs[cur][rbOff[j]];
#pragma unroll
        for (int i = 0; i < 4; i++)
#pragma unroll
            for (int j = 0; j < NJ; j++)
                acc[i][j] = __builtin_amdgcn_mfma_f32_16x16x32_bf16(af[i], bfr[j],
                                                                    acc[i][j], 0, 0, 0);
    }

    const int mBase = m0 + wm * 64 + quad * 4;
    const int nBase = n0 + wn * (BN / 2) + lr;
#pragma unroll
    for (int i = 0; i < 4; i++) {
#pragma unroll
        for (int j = 0; j < NJ; j++) {
            int n = nBase + j * 16;
#pragma unroll
            for (int r = 0; r < 4; r++) {
                int m = mBase + i * 16 + r;
                float v = acc[i][j][r];
                if (MODE == 0) {
                    float rr = v + bias[n];
                    rr = fminf(fmaxf(rr, -10.f), 10.f);
                    ((float*)Cv)[(size_t)m * Nn + n] = fast_softplus(rr);
                } else if (MODE == 1) {
                    ((__bf16*)Cv)[(size_t)m * Nn + n] = (__bf16)fast_gelu(v);
                } else {
                    ((float*)Cv)[(size_t)m * Nn + n] += v;
                }
            }
        }
    }
}

// ---------------------------------------------------------------------------
// Fused top-8 + dynamic path: one block (256 thr) per token.
// ---------------------------------------------------------------------------
__global__ __launch_bounds__(256) void topk_dyn_kernel(
        const float* __restrict__ alpha,
        const float* __restrict__ x,
        const float* __restrict__ unitU,
        const float* __restrict__ unitV,
        const float* __restrict__ gamma,
        float* __restrict__ out) {
    int n = blockIdx.x;
    int t = threadIdx.x;
    int lane = t & 63, wid = t >> 6;

    __shared__ int   sidx[8];
    __shared__ float shz[8];
    __shared__ float red[8][4];
    __shared__ float hz[8];

    if (wid == 0) {
        const float* row = alpha + (size_t)n * NBLK;
        float v[8];
#pragma unroll
        for (int i = 0; i < 8; i++) v[i] = row[lane + i * 64];
        float topv[8];
        int   topi[8];
        for (int s = 0; s < 8; s++) {
            float bv = v[0]; int bi = 0;
#pragma unroll
            for (int i = 1; i < 8; i++)
                if (v[i] > bv) { bv = v[i]; bi = i; }
            int gidx = lane + bi * 64;
#pragma unroll
            for (int off = 1; off < 64; off <<= 1) {
                float ov = __shfl_xor(bv, off, 64);
                int   oi = __shfl_xor(gidx, off, 64);
                if (ov > bv || (ov == bv && oi < gidx)) { bv = ov; gidx = oi; }
            }
            topv[s] = bv; topi[s] = gidx;
            if ((gidx & 63) == lane) v[gidx >> 6] = -1e30f;
        }
        float S = 0.f;
#pragma unroll
        for (int s = 0; s < 8; s++) S += topv[s];
        float zscale = tanhf(S) / (S + 1e-6f);
        if (lane < 8) {
            sidx[lane] = topi[lane];
            shz[lane]  = topv[lane] * zscale;
        }
    }
    __syncthreads();

    const float* xr = x + (size_t)n * DDIM;
    float xv[4];
#pragma unroll
    for (int i = 0; i < 4; i++) xv[i] = xr[t + i * 256];

    float acc[8];
#pragma unroll
    for (int k = 0; k < 8; k++) {
        const float* ur = unitU + (size_t)sidx[k] * DDIM;
        float a = 0.f;
#pragma unroll
        for (int i = 0; i < 4; i++) a = fmaf(xv[i], ur[t + i * 256], a);
        acc[k] = a;
    }
#pragma unroll
    for (int k = 0; k < 8; k++) {
        float a = wave_reduce_sum(acc[k]);
        if (lane == 0) red[k][wid] = a;
    }
    __syncthreads();
    if (t < 8) {
        float h = red[t][0] + red[t][1] + red[t][2] + red[t][3];
        hz[t] = h * shz[t];
    }
    __syncthreads();

    float* orow = out + (size_t)n * DDIM;
#pragma unroll
    for (int i = 0; i < 4; i++) {
        int d = t + i * 256;
        float s = 0.f;
#pragma unroll
        for (int k = 0; k < 8; k++)
            s = fmaf(hz[k], unitV[(size_t)sidx[k] * DDIM + d], s);
        orow[d] = s * gamma[d];
    }
}

// ---------------------------------------------------------------------------
extern "C" void kernel_launch(void* const* d_in, const int* in_sizes, int n_in,
                              void* d_out, int out_size, void* d_ws, size_t ws_size,
                              hipStream_t stream) {
    const float* x        = (const float*)d_in[0];
    const float* W1       = (const float*)d_in[1];
    const float* W2       = (const float*)d_in[2];
    const float* ln_g     = (const float*)d_in[3];
    const float* ln_b     = (const float*)d_in[4];
    const float* router_W = (const float*)d_in[5];
    const float* router_b = (const float*)d_in[6];
    const float* raw_U    = (const float*)d_in[7];
    const float* raw_V    = (const float*)d_in[8];
    const float* gamma    = (const float*)d_in[9];
    float* out = (float*)d_out;

    char* ws = (char*)d_ws;
    __bf16* lnb   = (__bf16*)(ws);                 // 16,777,216 B
    float*  alpha = (float*)(ws + 16777216u);      // 16,777,216 B
    __bf16* g1    = (__bf16*)(ws);                 // 67,108,864 B (after topk_dyn)
    __bf16* xb    = (__bf16*)(ws + 67108864u);     // 16,777,216 B
    __bf16* w1b   = (__bf16*)(ws + 83886080u);     //  8,388,608 B
    __bf16* w2b   = (__bf16*)(ws + 92274688u);     //  8,388,608 B
    __bf16* rwb   = (__bf16*)(ws + 100663296u);    //  1,048,576 B
    float*  unitU = (float*)(ws + 101711872u);     //  2,097,152 B
    float*  unitV = (float*)(ws + 103809024u);     //  2,097,152 B

    prep_kernel<<<17920, 256, 0, stream>>>(x, ln_g, ln_b, W1, W2, router_W,
                                           raw_U, raw_V, xb, lnb, w1b, w2b, rwb,
                                           unitU, unitV);

    // router: [8192,512] = lnb @ rwb^T, softplus epilogue. BN=64 -> 512 blocks.
    dim3 gR(N_TOK / 128, NBLK / 64);
    mfma_gemm<0, 64><<<gR, 256, 0, stream>>>(lnb, rwb, router_b, (void*)alpha,
                                             N_TOK, NBLK, DDIM);

    // fused top-8 + dynamic path (overwrites out)
    topk_dyn_kernel<<<N_TOK, 256, 0, stream>>>(alpha, x, unitU, unitV, gamma, out);

    // gemm1: g1 = gelu(x @ W1^T) -> bf16. BN=128 (already 2048 blocks).
    dim3 g1d(N_TOK / 128, HDIM / 128);
    mfma_gemm<1, 128><<<g1d, 256, 0, stream>>>(xb, w1b, nullptr, (void*)g1,
                                               N_TOK, HDIM, DDIM);

    // gemm2: out += g1 @ W2^T. BN=64 -> 1024 blocks (was 512 = 2/CU starved).
    dim3 g2d(N_TOK / 128, DDIM / 64);
    mfma_gemm<2, 64><<<g2d, 256, 0, stream>>>(g1, w2b, nullptr, (void*)out,
                                              N_TOK, DDIM, HDIM);
}